// Round 1
// baseline (39.307 us; speedup 1.0000x reference)
//
#include <hip/hip_runtime.h>

// Depthwise 7x7 'same' conv, fp32. B=16, C=256, H=W=64.
// One block per (b,c) plane. Whole plane staged in zero-padded LDS:
//   rows 0..69  = input rows -3..66 (zero outside [0,64))
//   cols: data at [4..67], zero halo left [0..3] and right [68..79]
// LDSW=80 so every float4 access (fill and compute reads) is 16B-aligned
// and row stride (320B) keeps bank usage uniform.
#define LDSW 80
#define LDSH 70
#define KSZ 7
#define PAD 3

__global__ __launch_bounds__(256, 4)
void dwconv7x7_kernel(const float* __restrict__ x,
                      const float* __restrict__ weight,
                      const float* __restrict__ bias,
                      float* __restrict__ out) {
    __shared__ float tile[LDSH * LDSW];

    const int bc  = blockIdx.x;       // b*256 + c
    const int c   = bc & 255;
    const int tid = threadIdx.x;

    // ---- zero the whole LDS tile (float4-granular, 1400 float4 total) ----
    const float4 z4 = make_float4(0.f, 0.f, 0.f, 0.f);
#pragma unroll
    for (int k = 0; k < 6; ++k) {
        int g = tid + k * 256;
        if (g < (LDSH * LDSW) / 4)
            *reinterpret_cast<float4*>(&tile[g * 4]) = z4;
    }

    // ---- per-channel weights + bias (wave-uniform address -> scalar loads) ----
    const float* wp = weight + c * (KSZ * KSZ);
    float wk[KSZ * KSZ];
#pragma unroll
    for (int k = 0; k < KSZ * KSZ; ++k) wk[k] = wp[k];
    const float bv = bias[c];

    __syncthreads();

    // ---- stage the 64x64 plane into LDS (coalesced float4) ----
    const float* xp = x + (size_t)bc * 4096;
#pragma unroll
    for (int k = 0; k < 4; ++k) {
        int g = tid + k * 256;               // float4 index in plane, 1024 total
        int h = g >> 4;                      // (g*4)/64
        int w = (g & 15) * 4;
        float4 v = *reinterpret_cast<const float4*>(&xp[g * 4]);
        *reinterpret_cast<float4*>(&tile[(h + PAD) * LDSW + (w + 4)]) = v;
    }
    __syncthreads();

    // ---- each thread computes a 4x4 output tile ----
    const int tx = tid & 15;                 // 16 tiles across width
    const int ty = tid >> 4;                 // 16 tiles down height
    const int wb = tx * 4;
    const int hb = ty * 4;

    float acc[4][4];
#pragma unroll
    for (int i = 0; i < 4; ++i)
#pragma unroll
        for (int j = 0; j < 4; ++j) acc[i][j] = 0.f;

    // Input rows needed: hb-3 .. hb+6  -> LDS rows hb .. hb+9
    // Input cols needed: wb-3 .. wb+6  -> LDS cols wb+1 .. wb+10
    // Read 3 aligned float4 per row covering LDS cols [wb, wb+12).
#pragma unroll
    for (int r = 0; r < 10; ++r) {
        const float* row = &tile[(hb + r) * LDSW + wb];
        float4 q0 = *reinterpret_cast<const float4*>(row);
        float4 q1 = *reinterpret_cast<const float4*>(row + 4);
        float4 q2 = *reinterpret_cast<const float4*>(row + 8);
        float f[12] = {q0.x, q0.y, q0.z, q0.w,
                       q1.x, q1.y, q1.z, q1.w,
                       q2.x, q2.y, q2.z, q2.w};
#pragma unroll
        for (int i = 0; i < 4; ++i) {
            // row r contributes to output row i iff 0 <= r-i <= 6 (kernel row kr=r-i)
            if (r - i >= 0 && r - i <= 6) {
                const int kr = r - i;
#pragma unroll
                for (int j = 0; j < 4; ++j) {
#pragma unroll
                    for (int kc = 0; kc < KSZ; ++kc) {
                        acc[i][j] += f[j + 1 + kc] * wk[kr * KSZ + kc];
                    }
                }
            }
        }
    }

    // ---- write 4x4 tile (one float4 per row, coalesced within wave) ----
    float* op = out + (size_t)bc * 4096;
#pragma unroll
    for (int i = 0; i < 4; ++i) {
        float4 v;
        v.x = acc[i][0] + bv;
        v.y = acc[i][1] + bv;
        v.z = acc[i][2] + bv;
        v.w = acc[i][3] + bv;
        *reinterpret_cast<float4*>(&op[(hb + i) * 64 + wb]) = v;
    }
}

extern "C" void kernel_launch(void* const* d_in, const int* in_sizes, int n_in,
                              void* d_out, int out_size, void* d_ws, size_t ws_size,
                              hipStream_t stream) {
    const float* x      = (const float*)d_in[0];
    const float* weight = (const float*)d_in[1];
    const float* bias   = (const float*)d_in[2];
    float* out          = (float*)d_out;
    (void)in_sizes; (void)n_in; (void)out_size; (void)d_ws; (void)ws_size;

    dim3 grid(16 * 256);   // one block per (b, c) plane
    dim3 block(256);
    dwconv7x7_kernel<<<grid, block, 0, stream>>>(x, weight, bias, out);
}

// Round 2
// 34.813 us; speedup vs baseline: 1.1291x; 1.1291x over previous
//
#include <hip/hip_runtime.h>

// Depthwise 7x7 'same' conv, fp32. B=16, C=256, H=W=64.
// No LDS. One wave per half-plane (8192 waves). Each lane owns a
// 4-wide x 8-high output tile, output-stationary in 32 VGPRs, streaming
// 14 input rows directly from global (L1/L2/L3 absorb the 49x reuse).
// Weights are wave-uniform (readfirstlane -> SGPR file, 49 floats).

__global__ void dwconv7x7_regs(const float* __restrict__ x,
                               const float* __restrict__ weight,
                               const float* __restrict__ bias,
                               float* __restrict__ out) {
    const int tid  = threadIdx.x;
    const int lane = tid & 63;
    const int wid  = tid >> 6;
    const int gw   = blockIdx.x * 4 + wid;   // 0..8191
    const int plane = gw >> 1;               // b*256 + c
    const int half  = gw & 1;
    const int c = __builtin_amdgcn_readfirstlane(plane & 255);

    // ---- per-channel weights + bias (uniform -> scalar regs/loads) ----
    const float* wp = weight + c * 49;
    float wk[49];
#pragma unroll
    for (int k = 0; k < 49; ++k) wk[k] = wp[k];
    const float bv = bias[c];

    const int tx = lane & 15;        // 16 tiles across width
    const int sy = lane >> 4;        // 4 strips per half-plane
    const int wb = tx * 4;           // output col base
    const int hb = half * 32 + sy * 8;  // output row base

    const float* xp = x + (size_t)plane * 4096;

    float acc[8][4];
#pragma unroll
    for (int i = 0; i < 8; ++i)
#pragma unroll
        for (int j = 0; j < 4; ++j) acc[i][j] = 0.f;

    const int offm = (tx > 0)  ? (wb - 4) : wb;   // clamped aligned left read
    const int offp = (tx < 15) ? (wb + 4) : wb;   // clamped aligned right read

    // Stream input rows hb-3 .. hb+10. Row r contributes to output rows
    // oi with kr = j - oi in [0,7).
#pragma unroll
    for (int j = 0; j < 14; ++j) {
        const int r  = hb - 3 + j;
        const int rc = min(max(r, 0), 63);
        const float* rowp = xp + rc * 64;
        const bool mrow = (r >= 0) && (r < 64);
        const bool mm = mrow && (tx > 0);
        const bool mp = mrow && (tx < 15);

        float4 q0 = *reinterpret_cast<const float4*>(rowp + wb);
        float4 qm = *reinterpret_cast<const float4*>(rowp + offm);
        float4 qp = *reinterpret_cast<const float4*>(rowp + offp);

        float f[12];
        f[0]  = mm   ? qm.x : 0.f;
        f[1]  = mm   ? qm.y : 0.f;
        f[2]  = mm   ? qm.z : 0.f;
        f[3]  = mm   ? qm.w : 0.f;
        f[4]  = mrow ? q0.x : 0.f;
        f[5]  = mrow ? q0.y : 0.f;
        f[6]  = mrow ? q0.z : 0.f;
        f[7]  = mrow ? q0.w : 0.f;
        f[8]  = mp   ? qp.x : 0.f;
        f[9]  = mp   ? qp.y : 0.f;
        f[10] = mp   ? qp.z : 0.f;
        f[11] = mp   ? qp.w : 0.f;

        // window f covers input cols wb-4 .. wb+7; needed: wb-3 .. wb+6
        // output col wb+jj, tap kc -> input col wb+jj-3+kc = f[1+jj+kc]
#pragma unroll
        for (int oi = 0; oi < 8; ++oi) {
            const int kr = j - oi;
            if (kr >= 0 && kr < 7) {
#pragma unroll
                for (int jj = 0; jj < 4; ++jj) {
#pragma unroll
                    for (int kc = 0; kc < 7; ++kc) {
                        acc[oi][jj] += f[1 + jj + kc] * wk[kr * 7 + kc];
                    }
                }
            }
        }
    }

    // ---- write 8 rows x float4, plus bias ----
    float* op = out + (size_t)plane * 4096 + (size_t)hb * 64 + wb;
#pragma unroll
    for (int oi = 0; oi < 8; ++oi) {
        float4 v;
        v.x = acc[oi][0] + bv;
        v.y = acc[oi][1] + bv;
        v.z = acc[oi][2] + bv;
        v.w = acc[oi][3] + bv;
        *reinterpret_cast<float4*>(op + oi * 64) = v;
    }
}

extern "C" void kernel_launch(void* const* d_in, const int* in_sizes, int n_in,
                              void* d_out, int out_size, void* d_ws, size_t ws_size,
                              hipStream_t stream) {
    const float* x      = (const float*)d_in[0];
    const float* weight = (const float*)d_in[1];
    const float* bias   = (const float*)d_in[2];
    float* out          = (float*)d_out;
    (void)in_sizes; (void)n_in; (void)out_size; (void)d_ws; (void)ws_size;

    // 8192 waves = 2048 blocks x 256 threads (4 waves/block)
    dim3 grid(2048);
    dim3 block(256);
    dwconv7x7_regs<<<grid, block, 0, stream>>>(x, weight, bias, out);
}